// Round 1
// baseline (3162.004 us; speedup 1.0000x reference)
//
#include <hip/hip_runtime.h>

// L1 loss: sum(|out - target|) / N_VEH over fp32 [8388608, 8].
// R3 (prev session): flat one-float4-per-thread stage1 at fill-kernel BW; 3
// launches; 489 us. R4 theory: rocprof top-5 is ALL harness fillBufferAligned
// (1 GiB ws poison, 160 us each) -- our kernels are each <158 us, and ideal
// stage1 is ~85 us. The measured 490 us is dominated by fixed harness cost.
// Only controllable lever left: launch count. Fuse 3 kernels -> 1 kernel +
// 16-byte memset, last-block finalization via device-scope atomics.
// Accumulate block sums in DOUBLE (global_atomic_add_f64) so atomic ordering
// jitter (~1e-16 rel) disappears on the final cast to fp32.

#define NTHREADS 256

__global__ __launch_bounds__(NTHREADS) void l1_fused(
    const float4* __restrict__ a, const float4* __restrict__ b,
    double* __restrict__ acc, unsigned int* __restrict__ counter,
    float* __restrict__ out, int n4, unsigned int nblocks, double inv_n) {
    const int tid = blockIdx.x * NTHREADS + threadIdx.x;
    float s = 0.0f;
    if (tid < n4) {
        float4 x = a[tid];
        float4 y = b[tid];
        s = fabsf(x.x - y.x) + fabsf(x.y - y.y) +
            fabsf(x.z - y.z) + fabsf(x.w - y.w);
    }
    // wave64 butterfly-free down-reduce
    #pragma unroll
    for (int off = 32; off > 0; off >>= 1)
        s += __shfl_down(s, off, 64);
    __shared__ float smem[NTHREADS / 64];
    const int lane = threadIdx.x & 63;
    const int wave = threadIdx.x >> 6;
    if (lane == 0) smem[wave] = s;
    __syncthreads();
    if (threadIdx.x == 0) {
        float t = 0.0f;
        #pragma unroll
        for (int w = 0; w < NTHREADS / 64; ++w) t += smem[w];
        // device-scope f64 atomic: cross-XCD coherent [learn_hip m20]
        atomicAdd(acc, (double)t);
        __threadfence();  // order the acc-add before the ticket for all observers
        unsigned int ticket = atomicAdd(counter, 1u);
        if (ticket == nblocks - 1u) {
            // last block: coherent read of the full sum via atomic RMW
            double total = atomicAdd(acc, 0.0);
            out[0] = (float)(total * inv_n);
        }
    }
}

extern "C" void kernel_launch(void* const* d_in, const int* in_sizes, int n_in,
                              void* d_out, int out_size, void* d_ws, size_t ws_size,
                              hipStream_t stream) {
    const float* a = (const float*)d_in[0];   // out
    const float* b = (const float*)d_in[1];   // target
    float* out = (float*)d_out;

    int n = in_sizes[0];          // 67,108,864 floats
    int n4 = n >> 2;              // 16,777,216 float4 pairs
    int n_veh = n >> 3;           // 8,388,608 rows
    double inv_n = 1.0 / (double)n_veh;

    unsigned int nb = (unsigned int)((n4 + NTHREADS - 1) / NTHREADS);  // 65536

    double* acc = (double*)d_ws;                       // 8 B
    unsigned int* counter = (unsigned int*)((char*)d_ws + 8);  // 4 B

    // zero acc + counter (12 B, round to 16); memset is graph-capturable
    hipMemsetAsync(d_ws, 0, 16, stream);
    l1_fused<<<nb, NTHREADS, 0, stream>>>((const float4*)a, (const float4*)b,
                                          acc, counter, out, n4, nb, inv_n);
}

// Round 2
// 495.700 us; speedup vs baseline: 6.3789x; 6.3789x over previous
//
#include <hip/hip_runtime.h>

// L1 loss: sum(|out - target|) / N_VEH over fp32 [8388608, 8].
// R3 (prev session): flat one-float4-per-thread stage1 at fill-kernel BW,
// 3 launches, 489 us.
// R4 FAILED: single-kernel fusion via per-block device atomics to ONE cache
// line (65536 blocks x {f64 atomic + threadfence + u32 ticket}) serialized at
// ~21 ns/op -> kernel 2830 us. Lesson: same-address atomic fan-in must not
// scale with grid size on MI355X (8 XCDs, cross-fabric RMW).
// R5: revert to atomic-free structure; fuse stage2+3 into ONE single-block
// finalize kernel (1024 thr, float4 reads of 64K partials = 256 KB, ~8 us).
// 3 launches -> 2, no memset, no atomics. Dispatch boundaries provide the
// release/acquire ordering for partials (same as the proven R0 version).

#define NTHREADS 256

__global__ __launch_bounds__(NTHREADS) void l1_stage1(
    const float4* __restrict__ a, const float4* __restrict__ b,
    float* __restrict__ partial, int n4) {
    const int tid = blockIdx.x * NTHREADS + threadIdx.x;
    float s = 0.0f;
    if (tid < n4) {
        float4 x = a[tid];
        float4 y = b[tid];
        s = fabsf(x.x - y.x) + fabsf(x.y - y.y) +
            fabsf(x.z - y.z) + fabsf(x.w - y.w);
    }
    #pragma unroll
    for (int off = 32; off > 0; off >>= 1)
        s += __shfl_down(s, off, 64);
    __shared__ float smem[NTHREADS / 64];
    const int lane = threadIdx.x & 63;
    const int wave = threadIdx.x >> 6;
    if (lane == 0) smem[wave] = s;
    __syncthreads();
    if (threadIdx.x == 0) {
        float t = 0.0f;
        #pragma unroll
        for (int w = 0; w < NTHREADS / 64; ++w) t += smem[w];
        partial[blockIdx.x] = t;
    }
}

// Single-block finalize: reduce `count4` float4 partials -> out[0] = sum/N.
// count4 = 16384 float4 (65536 floats): 16 float4 per thread at 1024 threads.
#define FTHREADS 1024

__global__ __launch_bounds__(FTHREADS) void l1_finalize(
    const float4* __restrict__ in, float* __restrict__ out,
    int count4, float inv_n) {
    float s = 0.0f;
    for (int i = threadIdx.x; i < count4; i += FTHREADS) {
        float4 v = in[i];
        s += v.x + v.y + v.z + v.w;
    }
    #pragma unroll
    for (int off = 32; off > 0; off >>= 1)
        s += __shfl_down(s, off, 64);
    __shared__ double smem[FTHREADS / 64];
    const int lane = threadIdx.x & 63;
    const int wave = threadIdx.x >> 6;
    if (lane == 0) smem[wave] = (double)s;
    __syncthreads();
    if (threadIdx.x == 0) {
        double t = 0.0;
        #pragma unroll
        for (int w = 0; w < FTHREADS / 64; ++w) t += smem[w];
        out[0] = (float)(t * (double)inv_n);
    }
}

extern "C" void kernel_launch(void* const* d_in, const int* in_sizes, int n_in,
                              void* d_out, int out_size, void* d_ws, size_t ws_size,
                              hipStream_t stream) {
    const float* a = (const float*)d_in[0];   // out
    const float* b = (const float*)d_in[1];   // target
    float* out = (float*)d_out;

    int n = in_sizes[0];          // 67,108,864 floats
    int n4 = n >> 2;              // 16,777,216 float4 pairs
    int n_veh = n >> 3;           // 8,388,608 rows
    float inv_n = 1.0f / (float)n_veh;

    int nb1 = (n4 + NTHREADS - 1) / NTHREADS;          // 65536 partials
    int count4 = nb1 >> 2;                             // 16384 float4

    float* p1 = (float*)d_ws;                          // nb1 floats

    l1_stage1<<<nb1, NTHREADS, 0, stream>>>((const float4*)a, (const float4*)b, p1, n4);
    l1_finalize<<<1, FTHREADS, 0, stream>>>((const float4*)p1, out, count4, inv_n);
}